// Round 10
// baseline (323.372 us; speedup 1.0000x reference)
//
#include <hip/hip_runtime.h>
#include <cstdint>
#include <cstddef>

typedef unsigned short u16;
typedef unsigned int   u32;
typedef __attribute__((ext_vector_type(8))) short short8;
typedef __attribute__((ext_vector_type(4))) float floatx4;

__device__ __forceinline__ float asf(u32 u){ union{u32 u; float f;} v; v.u=u; return v.f; }
__device__ __forceinline__ u32 asu(float f){ union{float f; u32 u;} v; v.f=f; return v.u; }
__device__ __forceinline__ u16 f2bf(float f){ u32 u = asu(f); u32 r = u + 0x7FFFu + ((u>>16)&1u); return (u16)(r>>16); }
// fast bf16: round-to-nearest, ties away (2 VALU ops)
__device__ __forceinline__ u16 f2bf_fast(float f){ return (u16)((asu(f) + 0x8000u)>>16); }
__device__ __forceinline__ u32 pack2(float a, float b){ return (u32)f2bf(a) | (((u32)f2bf(b))<<16); }
__device__ __forceinline__ void bf8f(uint4 d, float* o){
  o[0]=asf(d.x<<16); o[1]=asf(d.x&0xFFFF0000u);
  o[2]=asf(d.y<<16); o[3]=asf(d.y&0xFFFF0000u);
  o[4]=asf(d.z<<16); o[5]=asf(d.z&0xFFFF0000u);
  o[6]=asf(d.w<<16); o[7]=asf(d.w&0xFFFF0000u);
}

#define SC2 0.25503485966f   // 32^-0.5 * log2(e) — folded into Q at QKV epilogue

// ---------------------------------------------------------------------------
// fp32 -> bf16 weight conversion, ALL weights in one launch.
// ---------------------------------------------------------------------------
__global__ __launch_bounds__(256) void cvt_all(
    const float* __restrict__ Wq, const float* __restrict__ Wk,
    const float* __restrict__ Wv, const float* __restrict__ Wo,
    const float* __restrict__ W1, const float* __restrict__ W2,
    u16* __restrict__ Wqkv, u16* __restrict__ Wob,
    u16* __restrict__ W1b, u16* __restrict__ W2b)
{
  const int blk = blockIdx.x;
  const float* src; u16* dst; int off;
  if      (blk < 128)  { src = Wq; dst = Wqkv;          off = blk; }
  else if (blk < 256)  { src = Wk; dst = Wqkv + 262144; off = blk - 128; }
  else if (blk < 384)  { src = Wv; dst = Wqkv + 524288; off = blk - 256; }
  else if (blk < 512)  { src = Wo; dst = Wob;           off = blk - 384; }
  else if (blk < 1024) { src = W1; dst = W1b;           off = blk - 512; }
  else                 { src = W2; dst = W2b;           off = blk - 1024; }
  const int i = (off*256 + threadIdx.x)*8;
  const float4 a = *(const float4*)(src + i);
  const float4 b = *(const float4*)(src + i + 4);
  uint4 st;
  st.x = pack2(a.x, a.y); st.y = pack2(a.z, a.w);
  st.z = pack2(b.x, b.y); st.w = pack2(b.z, b.w);
  *(uint4*)(dst + i) = st;
}

// ---------------------------------------------------------------------------
// MFMA GEMM: C[M,N] = A[M,K] @ B[N,K]^T, bf16 in, fp32 accum.
// R17: BM x 128 tile, BK=32, double-buffered (1 barrier/step), LDS rows
// 32 u16 (64 B, 4x16B slots) XOR-swizzled BOTH sides (rule 21): linear LDS
// dest + pre-swizzled GLOBAL source chunk ((lane&3)^((lane>>3)&3)) + read
// slot (quad^((fr>>1)&3)) -> frag ds_read_b128 conflict-free (2-way floor).
// Same involution as attn Ks (verified R11-R16). LDS 24 KB -> 6 blocks/CU:
// combines R15's occupancy with R16's conflict-free reads.
// ---------------------------------------------------------------------------
enum { EPI_NONE=0, EPI_BIAS_GELU=1, EPI_BIAS_RES=2, EPI_QSCALE=3 };

template<int BM, int EPI, typename OutT>
__global__ __launch_bounds__(256) void gemm_bt(
    const u16* __restrict__ A, const u16* __restrict__ B,
    const float* __restrict__ bias, const float* __restrict__ res,
    OutT* __restrict__ C, int M, int N, int K)
{
  __shared__ u16 As[2][BM*32];    // [buf][row][32], swizzled slots
  __shared__ u16 Bs[2][128*32];
  const int tid  = threadIdx.x;
  const int wave = tid >> 6;
  const int lane = tid & 63;
  const int bm = blockIdx.y, bn = blockIdx.x;

  // staging: lane -> row (lane>>2) within a 16-row group, source 16B chunk
  // pre-swizzled: (lane&3) ^ ((lane>>3)&3)  [= chunk ^ (row>>1)&3]
  const int srow   = lane >> 2;
  const int schunk = ((lane&3) ^ ((lane>>3)&3)) * 8;
  const u16* Ag = A + (size_t)bm*BM*K;
  const u16* Bg = B + (size_t)bn*128*K;

  constexpr int WM = BM/2;          // wave M extent (64 or 32)
  constexpr int MI = WM/16;         // A-frag count (4 or 2)
  const int wm = (wave>>1)*WM;
  const int wn = (wave&1)*64;
  const int fr = lane & 15;
  const int quad = lane >> 4;

  floatx4 acc[MI][4] = {};

  #define G_STAGE(buf, kk)                                                        \
    do {                                                                          \
      _Pragma("unroll")                                                           \
      for (int ii = 0; ii < BM/64; ++ii)                                          \
        __builtin_amdgcn_global_load_lds(                                         \
            (__attribute__((address_space(1))) void*)(Ag + (size_t)(wave*(BM/4) + ii*16 + srow)*K + (kk) + schunk), \
            (__attribute__((address_space(3))) void*)(&As[buf][(wave*(BM/4) + ii*16)*32]), \
            16, 0, 0);                                                            \
      _Pragma("unroll")                                                           \
      for (int ii = 0; ii < 2; ++ii)                                              \
        __builtin_amdgcn_global_load_lds(                                         \
            (__attribute__((address_space(1))) void*)(Bg + (size_t)(wave*32 + ii*16 + srow)*K + (kk) + schunk), \
            (__attribute__((address_space(3))) void*)(&Bs[buf][(wave*32 + ii*16)*32]), \
            16, 0, 0);                                                            \
    } while (0)

  // prologue: stage k0=0 into buf 0; barrier drains vmcnt
  G_STAGE(0, 0);
  __syncthreads();

  const int aslot = (quad ^ ((fr>>1)&3)) * 8;   // read-side swizzled slot
  const int nsteps = K >> 5;
  for (int s = 0; s < nsteps; ++s) {
    const int cur = s & 1;
    if (s + 1 < nsteps) G_STAGE(cur^1, (s+1)*32);

    short8 af[MI], bfr[4];
    #pragma unroll
    for (int i=0;i<MI;i++) af[i]  = *(const short8*)(&As[cur][(wm + i*16 + fr)*32 + aslot]);
    #pragma unroll
    for (int j=0;j<4;j++)  bfr[j] = *(const short8*)(&Bs[cur][(wn + j*16 + fr)*32 + aslot]);
    #pragma unroll
    for (int i=0;i<MI;i++)
      #pragma unroll
      for (int j=0;j<4;j++)
        acc[i][j] = __builtin_amdgcn_mfma_f32_16x16x32_bf16(af[i], bfr[j], acc[i][j], 0, 0, 0);

    // one barrier: staging for s+1 complete (vmcnt drain) + all waves done
    // reading buf[cur] before it is overwritten at step s+1
    if (s + 1 < nsteps) __syncthreads();
  }
  #undef G_STAGE

  const int col0 = bn*128 + wn + fr;
  float bv[4] = {0.f,0.f,0.f,0.f};
  if constexpr (EPI == EPI_BIAS_GELU || EPI == EPI_BIAS_RES) {
    #pragma unroll
    for (int j=0;j<4;j++) bv[j] = bias[col0 + j*16];
  }
  const int rq = (lane>>4)*4;
  #pragma unroll
  for (int i=0;i<MI;i++){
    #pragma unroll
    for (int rr=0;rr<4;rr++){
      const int m = bm*BM + wm + i*16 + rq + rr;
      const size_t rowoff = (size_t)m*N;
      #pragma unroll
      for (int j=0;j<4;j++){
        float vv = acc[i][j][rr];
        const int n = col0 + j*16;
        if constexpr (EPI == EPI_BIAS_GELU){
          vv += bv[j];
          vv = 0.5f*vv*(1.f + erff(vv*0.70710678118654752f));
        } else if constexpr (EPI == EPI_BIAS_RES){
          vv += bv[j] + res[rowoff + n];
        } else if constexpr (EPI == EPI_QSCALE){
          if (n < 512) vv *= SC2;   // pre-scale Q so attn uses exp2 directly
        }
        if constexpr (sizeof(OutT) == 2) C[rowoff + n] = f2bf(vv);
        else                             C[rowoff + n] = vv;
      }
    }
  }
}

// ---------------------------------------------------------------------------
// LayerNorm over 512 (fp32 in, bf16 out), wave-per-row, 4 rows/block
// ---------------------------------------------------------------------------
__global__ __launch_bounds__(256) void ln512_kernel(
    const float* __restrict__ x, const float* __restrict__ w, const float* __restrict__ b,
    u16* __restrict__ out)
{
  const int row  = blockIdx.x*4 + (threadIdx.x>>6);
  const int lane = threadIdx.x & 63;
  const size_t base = (size_t)row*512 + lane*8;
  float v[8];
  { const float4 a = *(const float4*)(x + base);
    const float4 c = *(const float4*)(x + base + 4);
    v[0]=a.x; v[1]=a.y; v[2]=a.z; v[3]=a.w; v[4]=c.x; v[5]=c.y; v[6]=c.z; v[7]=c.w; }
  float s=0.f, sq=0.f;
  #pragma unroll
  for (int i=0;i<8;i++){ s += v[i]; sq += v[i]*v[i]; }
  for (int off=32; off>0; off>>=1){ s += __shfl_xor(s, off, 64); sq += __shfl_xor(sq, off, 64); }
  const float mu = s*(1.f/512.f);
  const float rs = rsqrtf(sq*(1.f/512.f) - mu*mu + 1e-5f);
  float o[8];
  #pragma unroll
  for (int i=0;i<8;i++)
    o[i] = (v[i]-mu)*rs*w[lane*8+i] + b[lane*8+i];
  uint4 st; st.x=pack2(o[0],o[1]); st.y=pack2(o[2],o[3]); st.z=pack2(o[4],o[5]); st.w=pack2(o[6],o[7]);
  *(uint4*)(out + base) = st;
}

// h = LN(ao)*w2+b2 + x (fp32 out) ; z = LN(h)*w3+b3 (bf16 out)
__global__ __launch_bounds__(256) void lnres_kernel(
    const u16* __restrict__ ao, const float* __restrict__ x,
    const float* __restrict__ w2, const float* __restrict__ b2,
    const float* __restrict__ w3, const float* __restrict__ b3,
    float* __restrict__ h, u16* __restrict__ z)
{
  const int row  = blockIdx.x*4 + (threadIdx.x>>6);
  const int lane = threadIdx.x & 63;
  const size_t base = (size_t)row*512 + lane*8;
  float a[8], xr[8];
  bf8f(*(const uint4*)(ao + base), a);
  { const float4 p = *(const float4*)(x + base);
    const float4 q = *(const float4*)(x + base + 4);
    xr[0]=p.x; xr[1]=p.y; xr[2]=p.z; xr[3]=p.w; xr[4]=q.x; xr[5]=q.y; xr[6]=q.z; xr[7]=q.w; }
  float s=0.f, sq=0.f;
  #pragma unroll
  for (int i=0;i<8;i++){ s += a[i]; sq += a[i]*a[i]; }
  for (int off=32; off>0; off>>=1){ s += __shfl_xor(s, off, 64); sq += __shfl_xor(sq, off, 64); }
  float mu = s*(1.f/512.f);
  float rs = rsqrtf(sq*(1.f/512.f) - mu*mu + 1e-5f);
  float hv[8];
  #pragma unroll
  for (int i=0;i<8;i++)
    hv[i] = (a[i]-mu)*rs*w2[lane*8+i] + b2[lane*8+i] + xr[i];
  { float4 p; p.x=hv[0]; p.y=hv[1]; p.z=hv[2]; p.w=hv[3];
    float4 q; q.x=hv[4]; q.y=hv[5]; q.z=hv[6]; q.w=hv[7];
    *(float4*)(h + base) = p; *(float4*)(h + base + 4) = q; }
  s=0.f; sq=0.f;
  #pragma unroll
  for (int i=0;i<8;i++){ s += hv[i]; sq += hv[i]*hv[i]; }
  for (int off=32; off>0; off>>=1){ s += __shfl_xor(s, off, 64); sq += __shfl_xor(sq, off, 64); }
  mu = s*(1.f/512.f);
  rs = rsqrtf(sq*(1.f/512.f) - mu*mu + 1e-5f);
  float zv[8];
  #pragma unroll
  for (int i=0;i<8;i++)
    zv[i] = (hv[i]-mu)*rs*w3[lane*8+i] + b3[lane*8+i];
  uint4 st; st.x=pack2(zv[0],zv[1]); st.y=pack2(zv[2],zv[3]); st.z=pack2(zv[4],zv[5]); st.w=pack2(zv[6],zv[7]);
  *(uint4*)(z + base) = st;
}

// LayerNorm over 2048 (bf16, in place safe)
__global__ __launch_bounds__(256) void ln2048_kernel(
    const u16* x, const float* __restrict__ w, const float* __restrict__ b,
    u16* out)
{
  const int row  = blockIdx.x*4 + (threadIdx.x>>6);
  const int lane = threadIdx.x & 63;
  const u16* xp = x + (size_t)row*2048;
  float v[32];
  #pragma unroll
  for (int g=0; g<4; ++g) bf8f(*(const uint4*)(xp + g*512 + lane*8), v + g*8);
  float s=0.f, sq=0.f;
  #pragma unroll
  for (int i=0;i<32;i++){ s += v[i]; sq += v[i]*v[i]; }
  for (int off=32; off>0; off>>=1){ s += __shfl_xor(s, off, 64); sq += __shfl_xor(sq, off, 64); }
  const float mu = s*(1.f/2048.f);
  const float rs = rsqrtf(sq*(1.f/2048.f) - mu*mu + 1e-5f);
  u16* op = out + (size_t)row*2048;
  #pragma unroll
  for (int g=0; g<4; ++g){
    float o[8];
    #pragma unroll
    for (int i=0;i<8;i++){
      const int idx = g*512 + lane*8 + i;
      o[i] = (v[g*8+i]-mu)*rs*w[idx] + b[idx];
    }
    uint4 st; st.x=pack2(o[0],o[1]); st.y=pack2(o[2],o[3]); st.z=pack2(o[4],o[5]); st.w=pack2(o[6],o[7]);
    *(uint4*)(op + g*512 + lane*8) = st;
  }
}

// ---------------------------------------------------------------------------
// V transpose: QKV[8192 tok][1536] (v at col 1024) -> Vt[bh 64][dim 64][key 1024].
// ---------------------------------------------------------------------------
__global__ __launch_bounds__(256) void transpose_v(
    const u16* __restrict__ QKV, u16* __restrict__ Vt)
{
  __shared__ __align__(16) u16 T[64][72];
  const int bid = blockIdx.x;
  const int bh  = bid >> 4;
  const int kt  = bid & 15;
  const int b   = bh >> 3;
  const int h   = bh & 7;
  const int tid = threadIdx.x;

  const int key = tid >> 2;
  const int dc  = (tid & 3) * 16;
  const u16* src = QKV + ((size_t)(b*1024 + kt*64 + key))*1536 + 1024 + h*64 + dc;
  const uint4 a0 = *(const uint4*)(src);
  const uint4 a1 = *(const uint4*)(src + 8);
  *(uint4*)(&T[key][dc])     = a0;
  *(uint4*)(&T[key][dc + 8]) = a1;
  __syncthreads();

  const int d  = tid >> 2;
  const int kc = (tid & 3) * 16;
  union { uint4 q[2]; u16 us[16]; } ow;
  #pragma unroll
  for (int i=0;i<16;i++) ow.us[i] = T[kc + i][d];
  u16* dst = Vt + ((size_t)(bh*64 + d))*1024 + kt*64 + kc;
  *(uint4*)(dst)     = ow.q[0];
  *(uint4*)(dst + 8) = ow.q[1];
}

// ---------------------------------------------------------------------------
// MFMA differential flash attention — R17: identical structure to R16
// (verified: dbuf K+V LDS, 1 barrier/tile, XCD-chunked swizzle).
// Change: Q is pre-scaled by SC2 upstream -> p = exp2f(s) (no per-P mul).
// ---------------------------------------------------------------------------
__global__ __launch_bounds__(256) void attn_mfma(
    const u16* __restrict__ QKV, const u16* __restrict__ Vt,
    const float* __restrict__ lq1, const float* __restrict__ lk1,
    const float* __restrict__ lq2, const float* __restrict__ lk2,
    const float* __restrict__ subw, u16* __restrict__ out)
{
  __shared__ __align__(16) u16 Ks1[2][64*32];   // [buf][key][dim 0..31]  8 KB
  __shared__ __align__(16) u16 Ks2[2][64*32];   // [buf][key][dim 32..63] 8 KB
  __shared__ __align__(16) u16 Vs [2][64*64];   // [buf][dim][key 0..63] 16 KB
  __shared__ __align__(16) u16 Ps [2][4][16*32];// [sub][wave][row*32]    8 KB

  const int tid  = threadIdx.x;
  const int wave = tid >> 6;
  const int lane = tid & 63;
  const int quad = lane >> 4;
  const int l15  = lane & 15;

  // XCD-chunked swizzle (T1, verified R16: FETCH 69.7->12.4 MB)
  const int bid = blockIdx.x;
  const int bh  = (bid & 7)*8 + ((bid >> 3) >> 4);
  const int qt  = (bid >> 3) & 15;
  const int b   = bh >> 3;
  const int h   = bh & 7;

  float t1 = 0.f, t2 = 0.f;
  for (int i=0;i<32;i++){ t1 += lq1[i]*lk1[i]; t2 += lq2[i]*lk2[i]; }
  const float lam = __expf(t1) - __expf(t2) + 0.2f;   // LAMBDA_INIT = 0.2

  const int qrowg = b*1024 + qt*64 + wave*16 + l15;
  const short8 aq1 = *(const short8*)(QKV + (size_t)qrowg*1536 + 2*h*32 + quad*8);
  const short8 aq2 = *(const short8*)(QKV + (size_t)qrowg*1536 + 2*h*32 + 32 + quad*8);

  floatx4 O1[4] = {}, O2[4] = {};
  float l1acc[4] = {0.f,0.f,0.f,0.f};
  float l2acc[4] = {0.f,0.f,0.f,0.f};
  const floatx4 zf4 = {0.f,0.f,0.f,0.f};

  const int kvbase = b*1024;
  u16* pw1 = &Ps[0][wave][0];
  u16* pw2 = &Ps[1][wave][0];

  const int kchunk = ((lane&3) ^ ((lane>>3)&3)) * 8;
  const u16* KbaseS = QKV + (size_t)(kvbase + wave*16 + (lane>>2))*1536 + 512 + 2*h*32 + kchunk;
  const int vchunk = ((lane&7) ^ (lane>>3)) * 8;
  const u16* VbaseS = Vt + ((size_t)bh*64 + wave*16 + (lane>>3))*1024 + vchunk;

  #define STAGE_TILE(buf, tt)                                                     \
    do {                                                                          \
      const u16* kp = KbaseS + (size_t)(tt)*64*1536;                              \
      __builtin_amdgcn_global_load_lds(                                           \
          (__attribute__((address_space(1))) void*)(kp),                          \
          (__attribute__((address_space(3))) void*)(&Ks1[buf][wave*16*32]), 16, 0, 0); \
      __builtin_amdgcn_global_load_lds(                                           \
          (__attribute__((address_space(1))) void*)(kp + 32),                     \
          (__attribute__((address_space(3))) void*)(&Ks2[buf][wave*16*32]), 16, 0, 0); \
      const u16* vp = VbaseS + (tt)*64;                                           \
      __builtin_amdgcn_global_load_lds(                                           \
          (__attribute__((address_space(1))) void*)(vp),                          \
          (__attribute__((address_space(3))) void*)(&Vs[buf][wave*16*64]), 16, 0, 0); \
      __builtin_amdgcn_global_load_lds(                                           \
          (__attribute__((address_space(1))) void*)(vp + (size_t)8*1024),         \
          (__attribute__((address_space(3))) void*)(&Vs[buf][(wave*16+8)*64]), 16, 0, 0); \
    } while (0)

  STAGE_TILE(0, 0);
  __syncthreads();

  const int kslotR = (quad ^ ((l15>>1)&3)) * 8;
  const int pslotR = ((quad + (l15>>2)) & 3) * 8;

  for (int t = 0; t < 16; ++t) {
    const int cur = t & 1;

    if (t < 15) STAGE_TILE(cur^1, t+1);

    #pragma unroll
    for (int kh = 0; kh < 2; ++kh) {
      #pragma unroll
      for (int ktl = 0; ktl < 2; ++ktl) {
        const int kt = kh*2 + ktl;
        const short8 bk1 = *(const short8*)(&Ks1[cur][(kt*16 + l15)*32 + kslotR]);
        const short8 bk2 = *(const short8*)(&Ks2[cur][(kt*16 + l15)*32 + kslotR]);
        const floatx4 s1 = __builtin_amdgcn_mfma_f32_16x16x32_bf16(aq1, bk1, zf4, 0, 0, 0);
        const floatx4 s2 = __builtin_amdgcn_mfma_f32_16x16x32_bf16(aq2, bk2, zf4, 0, 0, 0);
        const int wslot = ((ktl*2 + (l15>>3) + quad) & 3)*8;
        u16* d1 = pw1 + wslot + (l15&7);
        u16* d2 = pw2 + wslot + (l15&7);
        #pragma unroll
        for (int rr = 0; rr < 4; ++rr) {
          const float p1 = exp2f(s1[rr]);    // Q pre-scaled by SC2 upstream
          const float p2 = exp2f(s2[rr]);
          d1[(quad*4+rr)*32] = f2bf_fast(p1);
          d2[(quad*4+rr)*32] = f2bf_fast(p2);
          l1acc[rr] += p1;
          l2acc[rr] += p2;
        }
      }
      const short8 ap1 = *(const short8*)(pw1 + l15*32 + pslotR);
      const short8 ap2 = *(const short8*)(pw2 + l15*32 + pslotR);
      const int vslotR = ((kh*4 + quad) ^ (l15&7)) * 8;
      #pragma unroll
      for (int nt = 0; nt < 4; ++nt) {
        const short8 bv = *(const short8*)(&Vs[cur][(nt*16 + l15)*64 + vslotR]);
        O1[nt] = __builtin_amdgcn_mfma_f32_16x16x32_bf16(ap1, bv, O1[nt], 0, 0, 0);
        O2[nt] = __builtin_amdgcn_mfma_f32_16x16x32_bf16(ap2, bv, O2[nt], 0, 0, 0);
      }
    }

    if (t < 15) __syncthreads();
  }
  #undef STAGE_TILE

  #pragma unroll
  for (int rr=0; rr<4; ++rr){
    float v1 = l1acc[rr], v2 = l2acc[rr];
    v1 += __shfl_xor(v1, 1, 64); v2 += __shfl_xor(v2, 1, 64);
    v1 += __shfl_xor(v1, 2, 64); v2 += __shfl_xor(v2, 2, 64);
    v1 += __shfl_xor(v1, 4, 64); v2 += __shfl_xor(v2, 4, 64);
    v1 += __shfl_xor(v1, 8, 64); v2 += __shfl_xor(v2, 8, 64);
    l1acc[rr] = v1; l2acc[rr] = v2;
  }

  float sw[4];
  #pragma unroll
  for (int nt=0; nt<4; ++nt) sw[nt] = subw[nt*16 + l15];

  #pragma unroll
  for (int rr=0; rr<4; ++rr){
    const int row = quad*4 + rr;
    const float il1 = 1.f / l1acc[rr];
    const float cl2 = lam / l2acc[rr];
    float o[4]; float ss = 0.f;
    #pragma unroll
    for (int nt=0; nt<4; ++nt){
      o[nt] = O1[nt][rr]*il1 - O2[nt][rr]*cl2;
      ss += o[nt]*o[nt];
    }
    ss += __shfl_xor(ss, 1, 64);
    ss += __shfl_xor(ss, 2, 64);
    ss += __shfl_xor(ss, 4, 64);
    ss += __shfl_xor(ss, 8, 64);
    const float rs = rsqrtf(ss*(1.f/64.f) + 1e-5f) * 0.8f;
    const int orow = b*1024 + qt*64 + wave*16 + row;
    u16* op = out + (size_t)orow*512 + h*64 + l15;
    #pragma unroll
    for (int nt=0; nt<4; ++nt)
      op[nt*16] = f2bf(o[nt]*rs*sw[nt]);
  }
}

// ---------------------------------------------------------------------------
extern "C" void kernel_launch(void* const* d_in, const int* in_sizes, int n_in,
                              void* d_out, int out_size, void* d_ws, size_t ws_size,
                              hipStream_t stream)
{
  (void)in_sizes; (void)n_in; (void)out_size; (void)ws_size;
  const float* x    = (const float*)d_in[0];
  const float* Wq   = (const float*)d_in[1];
  const float* Wk   = (const float*)d_in[2];
  const float* Wv   = (const float*)d_in[3];
  const float* Wo   = (const float*)d_in[4];
  const float* lq1  = (const float*)d_in[5];
  const float* lk1  = (const float*)d_in[6];
  const float* lq2  = (const float*)d_in[7];
  const float* lk2  = (const float*)d_in[8];
  const float* subw = (const float*)d_in[9];
  const float* n1w  = (const float*)d_in[10];
  const float* n1b  = (const float*)d_in[11];
  const float* n2w  = (const float*)d_in[12];
  const float* n2b  = (const float*)d_in[13];
  const float* m1w  = (const float*)d_in[14];
  const float* m1b  = (const float*)d_in[15];
  const float* mW1  = (const float*)d_in[16];
  const float* mb1  = (const float*)d_in[17];
  const float* m2w  = (const float*)d_in[18];
  const float* m2b  = (const float*)d_in[19];
  const float* mW2  = (const float*)d_in[20];
  const float* mb2  = (const float*)d_in[21];
  float* out = (float*)d_out;   // fp32 output

  char* ws = (char*)d_ws;
  const size_t MB = (size_t)1 << 20;
  u16*  xn  = (u16*)(ws + 0*MB);
  u16*  qkv = (u16*)(ws + 8*MB);    // [8192][1536] bf16 = 24 MB -> [8,32)
  u16*  a   = (u16*)(ws + 0*MB);    // attn out, reuse xn
  u16*  ao  = (u16*)(ws + 8*MB);    // reuse qkv (dead after attn)
  u16*  z1  = (u16*)(ws + 16*MB);
  float* h  = (float*)(ws + 32*MB);
  u16*  vt  = (u16*)(ws + 32*MB);   // Vt[64][64][1024]; dead before h written
  u16*  t   = (u16*)(ws + 48*MB);   // [48,80), LN2048 in place
  u16* Wqkvb= (u16*)(ws + 80*MB);   // [1536][512] bf16 = 1.5 MB
  u16* Wob  = (u16*)(ws + 81*MB + 512*1024);
  u16* W1b  = (u16*)(ws + 82*MB);
  u16* W2b  = (u16*)(ws + 84*MB);

  const int M = 8192;

  cvt_all<<<1536, 256, 0, stream>>>(Wq, Wk, Wv, Wo, mW1, mW2, Wqkvb, Wob, W1b, W2b);

  ln512_kernel<<<2048, 256, 0, stream>>>(x, n1w, n1b, xn);

  gemm_bt<64,EPI_QSCALE,u16><<<dim3(12,128), 256, 0, stream>>>(xn, Wqkvb, nullptr, nullptr, qkv, M, 1536, 512);

  transpose_v<<<1024, 256, 0, stream>>>(qkv, vt);

  attn_mfma<<<1024, 256, 0, stream>>>(qkv, vt, lq1, lk1, lq2, lk2, subw, a);

  gemm_bt<64,EPI_NONE,u16><<<dim3(4,128), 256, 0, stream>>>(a, Wob, nullptr, nullptr, ao, M, 512, 512);

  lnres_kernel<<<2048, 256, 0, stream>>>(ao, x, n2w, n2b, m1w, m1b, h, z1);

  gemm_bt<64,EPI_BIAS_GELU,u16><<<dim3(16,128), 256, 0, stream>>>(z1, W1b, mb1, nullptr, t, M, 2048, 512);

  ln2048_kernel<<<2048, 256, 0, stream>>>(t, m2w, m2b, t);

  gemm_bt<64,EPI_BIAS_RES,float><<<dim3(4,128), 256, 0, stream>>>(t, W2b, mb2, h, out, M, 512, 2048);
}

// Round 11
// 310.867 us; speedup vs baseline: 1.0402x; 1.0402x over previous
//
#include <hip/hip_runtime.h>
#include <cstdint>
#include <cstddef>

typedef unsigned short u16;
typedef unsigned int   u32;
typedef __attribute__((ext_vector_type(8))) short short8;
typedef __attribute__((ext_vector_type(4))) float floatx4;

__device__ __forceinline__ float asf(u32 u){ union{u32 u; float f;} v; v.u=u; return v.f; }
__device__ __forceinline__ u32 asu(float f){ union{float f; u32 u;} v; v.f=f; return v.u; }
__device__ __forceinline__ u16 f2bf(float f){ u32 u = asu(f); u32 r = u + 0x7FFFu + ((u>>16)&1u); return (u16)(r>>16); }
// fast bf16: round-to-nearest, ties away (2 VALU ops)
__device__ __forceinline__ u16 f2bf_fast(float f){ return (u16)((asu(f) + 0x8000u)>>16); }
__device__ __forceinline__ u32 pack2(float a, float b){ return (u32)f2bf(a) | (((u32)f2bf(b))<<16); }
__device__ __forceinline__ void bf8f(uint4 d, float* o){
  o[0]=asf(d.x<<16); o[1]=asf(d.x&0xFFFF0000u);
  o[2]=asf(d.y<<16); o[3]=asf(d.y&0xFFFF0000u);
  o[4]=asf(d.z<<16); o[5]=asf(d.z&0xFFFF0000u);
  o[6]=asf(d.w<<16); o[7]=asf(d.w&0xFFFF0000u);
}

#define SC2 0.25503485966f   // 32^-0.5 * log2(e) — folded into Q at QKV epilogue

// ---------------------------------------------------------------------------
// fp32 -> bf16 weight conversion, ALL weights in one launch.
// ---------------------------------------------------------------------------
__global__ __launch_bounds__(256) void cvt_all(
    const float* __restrict__ Wq, const float* __restrict__ Wk,
    const float* __restrict__ Wv, const float* __restrict__ Wo,
    const float* __restrict__ W1, const float* __restrict__ W2,
    u16* __restrict__ Wqkv, u16* __restrict__ Wob,
    u16* __restrict__ W1b, u16* __restrict__ W2b)
{
  const int blk = blockIdx.x;
  const float* src; u16* dst; int off;
  if      (blk < 128)  { src = Wq; dst = Wqkv;          off = blk; }
  else if (blk < 256)  { src = Wk; dst = Wqkv + 262144; off = blk - 128; }
  else if (blk < 384)  { src = Wv; dst = Wqkv + 524288; off = blk - 256; }
  else if (blk < 512)  { src = Wo; dst = Wob;           off = blk - 384; }
  else if (blk < 1024) { src = W1; dst = W1b;           off = blk - 512; }
  else                 { src = W2; dst = W2b;           off = blk - 1024; }
  const int i = (off*256 + threadIdx.x)*8;
  const float4 a = *(const float4*)(src + i);
  const float4 b = *(const float4*)(src + i + 4);
  uint4 st;
  st.x = pack2(a.x, a.y); st.y = pack2(a.z, a.w);
  st.z = pack2(b.x, b.y); st.w = pack2(b.z, b.w);
  *(uint4*)(dst + i) = st;
}

// ---------------------------------------------------------------------------
// MFMA GEMM: C[M,N] = A[M,K] @ B[N,K]^T, bf16 in, fp32 accum.
// R18 = R15 config (measured-best residual 229.4): BM x 128 tile, BK=32,
// double-buffered K-steps (stage t+1 at top of t via global_load_lds, ONE
// barrier per step), linear LDS (2-phase structure hides read conflicts —
// T2 swizzle measured null here, consistent with the regime gate).
// LDS 24 KB -> 6 blocks/CU LDS-cap. Wave = (BM/2) x 64.
// ---------------------------------------------------------------------------
enum { EPI_NONE=0, EPI_BIAS_GELU=1, EPI_BIAS_RES=2, EPI_QSCALE=3 };

template<int BM, int EPI, typename OutT>
__global__ __launch_bounds__(256) void gemm_bt(
    const u16* __restrict__ A, const u16* __restrict__ B,
    const float* __restrict__ bias, const float* __restrict__ res,
    OutT* __restrict__ C, int M, int N, int K)
{
  __shared__ u16 As[2][BM*32];
  __shared__ u16 Bs[2][128*32];
  const int tid  = threadIdx.x;
  const int wave = tid >> 6;
  const int lane = tid & 63;
  const int bm = blockIdx.y, bn = blockIdx.x;

  const int srow = wave*16 + (lane>>2);
  const int scol = (lane&3)*8;
  const u16* Ag = A + (size_t)bm*BM*K;
  const u16* Bg = B + (size_t)bn*128*K;

  constexpr int WM = BM/2;          // wave M extent (64 or 32)
  constexpr int MI = WM/16;         // A-frag count (4 or 2)
  const int wm = (wave>>1)*WM;
  const int wn = (wave&1)*64;
  const int fr = lane & 15;
  const int fk = (lane>>4)*8;

  floatx4 acc[MI][4] = {};

  #define G_STAGE(buf, kk)                                                        \
    do {                                                                          \
      if constexpr (BM == 128) {                                                  \
        _Pragma("unroll")                                                         \
        for (int tt = 0; tt < 2; ++tt)                                            \
          __builtin_amdgcn_global_load_lds(                                       \
              (__attribute__((address_space(1))) void*)(Ag + (tt*64 + srow)*K + (kk) + scol), \
              (__attribute__((address_space(3))) void*)(&As[buf][(tt*64 + wave*16)*32]),      \
              16, 0, 0);                                                          \
      } else {                                                                    \
        __builtin_amdgcn_global_load_lds(                                         \
            (__attribute__((address_space(1))) void*)(Ag + srow*K + (kk) + scol), \
            (__attribute__((address_space(3))) void*)(&As[buf][wave*16*32]),      \
            16, 0, 0);                                                            \
      }                                                                           \
      _Pragma("unroll")                                                           \
      for (int tt = 0; tt < 2; ++tt)                                              \
        __builtin_amdgcn_global_load_lds(                                         \
            (__attribute__((address_space(1))) void*)(Bg + (tt*64 + srow)*K + (kk) + scol), \
            (__attribute__((address_space(3))) void*)(&Bs[buf][(tt*64 + wave*16)*32]),      \
            16, 0, 0);                                                            \
    } while (0)

  // prologue: stage k0=0 into buf 0; barrier drains vmcnt
  G_STAGE(0, 0);
  __syncthreads();

  const int nsteps = K >> 5;
  for (int s = 0; s < nsteps; ++s) {
    const int cur = s & 1;
    if (s + 1 < nsteps) G_STAGE(cur^1, (s+1)*32);

    short8 af[MI], bfr[4];
    #pragma unroll
    for (int i=0;i<MI;i++) af[i] = *(const short8*)(&As[cur][(wm + i*16 + fr)*32 + fk]);
    #pragma unroll
    for (int j=0;j<4;j++) bfr[j] = *(const short8*)(&Bs[cur][(wn + j*16 + fr)*32 + fk]);
    #pragma unroll
    for (int i=0;i<MI;i++)
      #pragma unroll
      for (int j=0;j<4;j++)
        acc[i][j] = __builtin_amdgcn_mfma_f32_16x16x32_bf16(af[i], bfr[j], acc[i][j], 0, 0, 0);

    // one barrier: staging for s+1 complete (vmcnt drain) + all waves done
    // reading buf[cur] before it is overwritten at step s+1
    if (s + 1 < nsteps) __syncthreads();
  }
  #undef G_STAGE

  const int col0 = bn*128 + wn + fr;
  float bv[4] = {0.f,0.f,0.f,0.f};
  if constexpr (EPI == EPI_BIAS_GELU || EPI == EPI_BIAS_RES) {
    #pragma unroll
    for (int j=0;j<4;j++) bv[j] = bias[col0 + j*16];
  }
  const int rq = (lane>>4)*4;
  #pragma unroll
  for (int i=0;i<MI;i++){
    #pragma unroll
    for (int rr=0;rr<4;rr++){
      const int m = bm*BM + wm + i*16 + rq + rr;
      const size_t rowoff = (size_t)m*N;
      #pragma unroll
      for (int j=0;j<4;j++){
        float vv = acc[i][j][rr];
        const int n = col0 + j*16;
        if constexpr (EPI == EPI_BIAS_GELU){
          vv += bv[j];
          vv = 0.5f*vv*(1.f + erff(vv*0.70710678118654752f));
        } else if constexpr (EPI == EPI_BIAS_RES){
          vv += bv[j] + res[rowoff + n];
        } else if constexpr (EPI == EPI_QSCALE){
          if (n < 512) vv *= SC2;   // pre-scale Q so attn uses exp2 directly
        }
        if constexpr (sizeof(OutT) == 2) C[rowoff + n] = f2bf(vv);
        else                             C[rowoff + n] = vv;
      }
    }
  }
}

// ---------------------------------------------------------------------------
// LayerNorm over 512 (fp32 in, bf16 out), wave-per-row, 4 rows/block
// ---------------------------------------------------------------------------
__global__ __launch_bounds__(256) void ln512_kernel(
    const float* __restrict__ x, const float* __restrict__ w, const float* __restrict__ b,
    u16* __restrict__ out)
{
  const int row  = blockIdx.x*4 + (threadIdx.x>>6);
  const int lane = threadIdx.x & 63;
  const size_t base = (size_t)row*512 + lane*8;
  float v[8];
  { const float4 a = *(const float4*)(x + base);
    const float4 c = *(const float4*)(x + base + 4);
    v[0]=a.x; v[1]=a.y; v[2]=a.z; v[3]=a.w; v[4]=c.x; v[5]=c.y; v[6]=c.z; v[7]=c.w; }
  float s=0.f, sq=0.f;
  #pragma unroll
  for (int i=0;i<8;i++){ s += v[i]; sq += v[i]*v[i]; }
  for (int off=32; off>0; off>>=1){ s += __shfl_xor(s, off, 64); sq += __shfl_xor(sq, off, 64); }
  const float mu = s*(1.f/512.f);
  const float rs = rsqrtf(sq*(1.f/512.f) - mu*mu + 1e-5f);
  float o[8];
  #pragma unroll
  for (int i=0;i<8;i++)
    o[i] = (v[i]-mu)*rs*w[lane*8+i] + b[lane*8+i];
  uint4 st; st.x=pack2(o[0],o[1]); st.y=pack2(o[2],o[3]); st.z=pack2(o[4],o[5]); st.w=pack2(o[6],o[7]);
  *(uint4*)(out + base) = st;
}

// h = LN(ao)*w2+b2 + x (fp32 out) ; z = LN(h)*w3+b3 (bf16 out)
__global__ __launch_bounds__(256) void lnres_kernel(
    const u16* __restrict__ ao, const float* __restrict__ x,
    const float* __restrict__ w2, const float* __restrict__ b2,
    const float* __restrict__ w3, const float* __restrict__ b3,
    float* __restrict__ h, u16* __restrict__ z)
{
  const int row  = blockIdx.x*4 + (threadIdx.x>>6);
  const int lane = threadIdx.x & 63;
  const size_t base = (size_t)row*512 + lane*8;
  float a[8], xr[8];
  bf8f(*(const uint4*)(ao + base), a);
  { const float4 p = *(const float4*)(x + base);
    const float4 q = *(const float4*)(x + base + 4);
    xr[0]=p.x; xr[1]=p.y; xr[2]=p.z; xr[3]=p.w; xr[4]=q.x; xr[5]=q.y; xr[6]=q.z; xr[7]=q.w; }
  float s=0.f, sq=0.f;
  #pragma unroll
  for (int i=0;i<8;i++){ s += a[i]; sq += a[i]*a[i]; }
  for (int off=32; off>0; off>>=1){ s += __shfl_xor(s, off, 64); sq += __shfl_xor(sq, off, 64); }
  float mu = s*(1.f/512.f);
  float rs = rsqrtf(sq*(1.f/512.f) - mu*mu + 1e-5f);
  float hv[8];
  #pragma unroll
  for (int i=0;i<8;i++)
    hv[i] = (a[i]-mu)*rs*w2[lane*8+i] + b2[lane*8+i] + xr[i];
  { float4 p; p.x=hv[0]; p.y=hv[1]; p.z=hv[2]; p.w=hv[3];
    float4 q; q.x=hv[4]; q.y=hv[5]; q.z=hv[6]; q.w=hv[7];
    *(float4*)(h + base) = p; *(float4*)(h + base + 4) = q; }
  s=0.f; sq=0.f;
  #pragma unroll
  for (int i=0;i<8;i++){ s += hv[i]; sq += hv[i]*hv[i]; }
  for (int off=32; off>0; off>>=1){ s += __shfl_xor(s, off, 64); sq += __shfl_xor(sq, off, 64); }
  mu = s*(1.f/512.f);
  rs = rsqrtf(sq*(1.f/512.f) - mu*mu + 1e-5f);
  float zv[8];
  #pragma unroll
  for (int i=0;i<8;i++)
    zv[i] = (hv[i]-mu)*rs*w3[lane*8+i] + b3[lane*8+i];
  uint4 st; st.x=pack2(zv[0],zv[1]); st.y=pack2(zv[2],zv[3]); st.z=pack2(zv[4],zv[5]); st.w=pack2(zv[6],zv[7]);
  *(uint4*)(z + base) = st;
}

// LayerNorm over 2048 (bf16, in place safe)
__global__ __launch_bounds__(256) void ln2048_kernel(
    const u16* x, const float* __restrict__ w, const float* __restrict__ b,
    u16* out)
{
  const int row  = blockIdx.x*4 + (threadIdx.x>>6);
  const int lane = threadIdx.x & 63;
  const u16* xp = x + (size_t)row*2048;
  float v[32];
  #pragma unroll
  for (int g=0; g<4; ++g) bf8f(*(const uint4*)(xp + g*512 + lane*8), v + g*8);
  float s=0.f, sq=0.f;
  #pragma unroll
  for (int i=0;i<32;i++){ s += v[i]; sq += v[i]*v[i]; }
  for (int off=32; off>0; off>>=1){ s += __shfl_xor(s, off, 64); sq += __shfl_xor(sq, off, 64); }
  const float mu = s*(1.f/2048.f);
  const float rs = rsqrtf(sq*(1.f/2048.f) - mu*mu + 1e-5f);
  u16* op = out + (size_t)row*2048;
  #pragma unroll
  for (int g=0; g<4; ++g){
    float o[8];
    #pragma unroll
    for (int i=0;i<8;i++){
      const int idx = g*512 + lane*8 + i;
      o[i] = (v[g*8+i]-mu)*rs*w[idx] + b[idx];
    }
    uint4 st; st.x=pack2(o[0],o[1]); st.y=pack2(o[2],o[3]); st.z=pack2(o[4],o[5]); st.w=pack2(o[6],o[7]);
    *(uint4*)(op + g*512 + lane*8) = st;
  }
}

// ---------------------------------------------------------------------------
// V transpose: QKV[8192 tok][1536] (v at col 1024) -> Vt[bh 64][dim 64][key 1024].
// ---------------------------------------------------------------------------
__global__ __launch_bounds__(256) void transpose_v(
    const u16* __restrict__ QKV, u16* __restrict__ Vt)
{
  __shared__ __align__(16) u16 T[64][72];
  const int bid = blockIdx.x;
  const int bh  = bid >> 4;
  const int kt  = bid & 15;
  const int b   = bh >> 3;
  const int h   = bh & 7;
  const int tid = threadIdx.x;

  const int key = tid >> 2;
  const int dc  = (tid & 3) * 16;
  const u16* src = QKV + ((size_t)(b*1024 + kt*64 + key))*1536 + 1024 + h*64 + dc;
  const uint4 a0 = *(const uint4*)(src);
  const uint4 a1 = *(const uint4*)(src + 8);
  *(uint4*)(&T[key][dc])     = a0;
  *(uint4*)(&T[key][dc + 8]) = a1;
  __syncthreads();

  const int d  = tid >> 2;
  const int kc = (tid & 3) * 16;
  union { uint4 q[2]; u16 us[16]; } ow;
  #pragma unroll
  for (int i=0;i<16;i++) ow.us[i] = T[kc + i][d];
  u16* dst = Vt + ((size_t)(bh*64 + d))*1024 + kt*64 + kc;
  *(uint4*)(dst)     = ow.q[0];
  *(uint4*)(dst + 8) = ow.q[1];
}

// ---------------------------------------------------------------------------
// MFMA differential flash attention — R18: structure identical to R16/R17
// (verified: dbuf K+V LDS, 1 barrier/tile, XCD-chunked swizzle, QSCALE'd Q).
// Change vs R17: exp2f (libm call, +30% VALU) -> __builtin_amdgcn_exp2f
// (bare v_exp_f32; numerics proven by R17's pass).
// ---------------------------------------------------------------------------
__global__ __launch_bounds__(256) void attn_mfma(
    const u16* __restrict__ QKV, const u16* __restrict__ Vt,
    const float* __restrict__ lq1, const float* __restrict__ lk1,
    const float* __restrict__ lq2, const float* __restrict__ lk2,
    const float* __restrict__ subw, u16* __restrict__ out)
{
  __shared__ __align__(16) u16 Ks1[2][64*32];   // [buf][key][dim 0..31]  8 KB
  __shared__ __align__(16) u16 Ks2[2][64*32];   // [buf][key][dim 32..63] 8 KB
  __shared__ __align__(16) u16 Vs [2][64*64];   // [buf][dim][key 0..63] 16 KB
  __shared__ __align__(16) u16 Ps [2][4][16*32];// [sub][wave][row*32]    8 KB

  const int tid  = threadIdx.x;
  const int wave = tid >> 6;
  const int lane = tid & 63;
  const int quad = lane >> 4;
  const int l15  = lane & 15;

  // XCD-chunked swizzle (T1, verified R16: FETCH 69.7->12.4 MB)
  const int bid = blockIdx.x;
  const int bh  = (bid & 7)*8 + ((bid >> 3) >> 4);
  const int qt  = (bid >> 3) & 15;
  const int b   = bh >> 3;
  const int h   = bh & 7;

  float t1 = 0.f, t2 = 0.f;
  for (int i=0;i<32;i++){ t1 += lq1[i]*lk1[i]; t2 += lq2[i]*lk2[i]; }
  const float lam = __expf(t1) - __expf(t2) + 0.2f;   // LAMBDA_INIT = 0.2

  const int qrowg = b*1024 + qt*64 + wave*16 + l15;
  const short8 aq1 = *(const short8*)(QKV + (size_t)qrowg*1536 + 2*h*32 + quad*8);
  const short8 aq2 = *(const short8*)(QKV + (size_t)qrowg*1536 + 2*h*32 + 32 + quad*8);

  floatx4 O1[4] = {}, O2[4] = {};
  float l1acc[4] = {0.f,0.f,0.f,0.f};
  float l2acc[4] = {0.f,0.f,0.f,0.f};
  const floatx4 zf4 = {0.f,0.f,0.f,0.f};

  const int kvbase = b*1024;
  u16* pw1 = &Ps[0][wave][0];
  u16* pw2 = &Ps[1][wave][0];

  const int kchunk = ((lane&3) ^ ((lane>>3)&3)) * 8;
  const u16* KbaseS = QKV + (size_t)(kvbase + wave*16 + (lane>>2))*1536 + 512 + 2*h*32 + kchunk;
  const int vchunk = ((lane&7) ^ (lane>>3)) * 8;
  const u16* VbaseS = Vt + ((size_t)bh*64 + wave*16 + (lane>>3))*1024 + vchunk;

  #define STAGE_TILE(buf, tt)                                                     \
    do {                                                                          \
      const u16* kp = KbaseS + (size_t)(tt)*64*1536;                              \
      __builtin_amdgcn_global_load_lds(                                           \
          (__attribute__((address_space(1))) void*)(kp),                          \
          (__attribute__((address_space(3))) void*)(&Ks1[buf][wave*16*32]), 16, 0, 0); \
      __builtin_amdgcn_global_load_lds(                                           \
          (__attribute__((address_space(1))) void*)(kp + 32),                     \
          (__attribute__((address_space(3))) void*)(&Ks2[buf][wave*16*32]), 16, 0, 0); \
      const u16* vp = VbaseS + (tt)*64;                                           \
      __builtin_amdgcn_global_load_lds(                                           \
          (__attribute__((address_space(1))) void*)(vp),                          \
          (__attribute__((address_space(3))) void*)(&Vs[buf][wave*16*64]), 16, 0, 0); \
      __builtin_amdgcn_global_load_lds(                                           \
          (__attribute__((address_space(1))) void*)(vp + (size_t)8*1024),         \
          (__attribute__((address_space(3))) void*)(&Vs[buf][(wave*16+8)*64]), 16, 0, 0); \
    } while (0)

  STAGE_TILE(0, 0);
  __syncthreads();

  const int kslotR = (quad ^ ((l15>>1)&3)) * 8;
  const int pslotR = ((quad + (l15>>2)) & 3) * 8;

  for (int t = 0; t < 16; ++t) {
    const int cur = t & 1;

    if (t < 15) STAGE_TILE(cur^1, t+1);

    #pragma unroll
    for (int kh = 0; kh < 2; ++kh) {
      #pragma unroll
      for (int ktl = 0; ktl < 2; ++ktl) {
        const int kt = kh*2 + ktl;
        const short8 bk1 = *(const short8*)(&Ks1[cur][(kt*16 + l15)*32 + kslotR]);
        const short8 bk2 = *(const short8*)(&Ks2[cur][(kt*16 + l15)*32 + kslotR]);
        const floatx4 s1 = __builtin_amdgcn_mfma_f32_16x16x32_bf16(aq1, bk1, zf4, 0, 0, 0);
        const floatx4 s2 = __builtin_amdgcn_mfma_f32_16x16x32_bf16(aq2, bk2, zf4, 0, 0, 0);
        const int wslot = ((ktl*2 + (l15>>3) + quad) & 3)*8;
        u16* d1 = pw1 + wslot + (l15&7);
        u16* d2 = pw2 + wslot + (l15&7);
        #pragma unroll
        for (int rr = 0; rr < 4; ++rr) {
          const float p1 = __builtin_amdgcn_exp2f(s1[rr]);  // Q pre-scaled by SC2
          const float p2 = __builtin_amdgcn_exp2f(s2[rr]);
          d1[(quad*4+rr)*32] = f2bf_fast(p1);
          d2[(quad*4+rr)*32] = f2bf_fast(p2);
          l1acc[rr] += p1;
          l2acc[rr] += p2;
        }
      }
      const short8 ap1 = *(const short8*)(pw1 + l15*32 + pslotR);
      const short8 ap2 = *(const short8*)(pw2 + l15*32 + pslotR);
      const int vslotR = ((kh*4 + quad) ^ (l15&7)) * 8;
      #pragma unroll
      for (int nt = 0; nt < 4; ++nt) {
        const short8 bv = *(const short8*)(&Vs[cur][(nt*16 + l15)*64 + vslotR]);
        O1[nt] = __builtin_amdgcn_mfma_f32_16x16x32_bf16(ap1, bv, O1[nt], 0, 0, 0);
        O2[nt] = __builtin_amdgcn_mfma_f32_16x16x32_bf16(ap2, bv, O2[nt], 0, 0, 0);
      }
    }

    if (t < 15) __syncthreads();
  }
  #undef STAGE_TILE

  #pragma unroll
  for (int rr=0; rr<4; ++rr){
    float v1 = l1acc[rr], v2 = l2acc[rr];
    v1 += __shfl_xor(v1, 1, 64); v2 += __shfl_xor(v2, 1, 64);
    v1 += __shfl_xor(v1, 2, 64); v2 += __shfl_xor(v2, 2, 64);
    v1 += __shfl_xor(v1, 4, 64); v2 += __shfl_xor(v2, 4, 64);
    v1 += __shfl_xor(v1, 8, 64); v2 += __shfl_xor(v2, 8, 64);
    l1acc[rr] = v1; l2acc[rr] = v2;
  }

  float sw[4];
  #pragma unroll
  for (int nt=0; nt<4; ++nt) sw[nt] = subw[nt*16 + l15];

  #pragma unroll
  for (int rr=0; rr<4; ++rr){
    const int row = quad*4 + rr;
    const float il1 = 1.f / l1acc[rr];
    const float cl2 = lam / l2acc[rr];
    float o[4]; float ss = 0.f;
    #pragma unroll
    for (int nt=0; nt<4; ++nt){
      o[nt] = O1[nt][rr]*il1 - O2[nt][rr]*cl2;
      ss += o[nt]*o[nt];
    }
    ss += __shfl_xor(ss, 1, 64);
    ss += __shfl_xor(ss, 2, 64);
    ss += __shfl_xor(ss, 4, 64);
    ss += __shfl_xor(ss, 8, 64);
    const float rs = rsqrtf(ss*(1.f/64.f) + 1e-5f) * 0.8f;
    const int orow = b*1024 + qt*64 + wave*16 + row;
    u16* op = out + (size_t)orow*512 + h*64 + l15;
    #pragma unroll
    for (int nt=0; nt<4; ++nt)
      op[nt*16] = f2bf(o[nt]*rs*sw[nt]);
  }
}

// ---------------------------------------------------------------------------
extern "C" void kernel_launch(void* const* d_in, const int* in_sizes, int n_in,
                              void* d_out, int out_size, void* d_ws, size_t ws_size,
                              hipStream_t stream)
{
  (void)in_sizes; (void)n_in; (void)out_size; (void)ws_size;
  const float* x    = (const float*)d_in[0];
  const float* Wq   = (const float*)d_in[1];
  const float* Wk   = (const float*)d_in[2];
  const float* Wv   = (const float*)d_in[3];
  const float* Wo   = (const float*)d_in[4];
  const float* lq1  = (const float*)d_in[5];
  const float* lk1  = (const float*)d_in[6];
  const float* lq2  = (const float*)d_in[7];
  const float* lk2  = (const float*)d_in[8];
  const float* subw = (const float*)d_in[9];
  const float* n1w  = (const float*)d_in[10];
  const float* n1b  = (const float*)d_in[11];
  const float* n2w  = (const float*)d_in[12];
  const float* n2b  = (const float*)d_in[13];
  const float* m1w  = (const float*)d_in[14];
  const float* m1b  = (const float*)d_in[15];
  const float* mW1  = (const float*)d_in[16];
  const float* mb1  = (const float*)d_in[17];
  const float* m2w  = (const float*)d_in[18];
  const float* m2b  = (const float*)d_in[19];
  const float* mW2  = (const float*)d_in[20];
  const float* mb2  = (const float*)d_in[21];
  float* out = (float*)d_out;   // fp32 output

  char* ws = (char*)d_ws;
  const size_t MB = (size_t)1 << 20;
  u16*  xn  = (u16*)(ws + 0*MB);
  u16*  qkv = (u16*)(ws + 8*MB);    // [8192][1536] bf16 = 24 MB -> [8,32)
  u16*  a   = (u16*)(ws + 0*MB);    // attn out, reuse xn
  u16*  ao  = (u16*)(ws + 8*MB);    // reuse qkv (dead after attn)
  u16*  z1  = (u16*)(ws + 16*MB);
  float* h  = (float*)(ws + 32*MB);
  u16*  vt  = (u16*)(ws + 32*MB);   // Vt[64][64][1024]; dead before h written
  u16*  t   = (u16*)(ws + 48*MB);   // [48,80), LN2048 in place
  u16* Wqkvb= (u16*)(ws + 80*MB);   // [1536][512] bf16 = 1.5 MB
  u16* Wob  = (u16*)(ws + 81*MB + 512*1024);
  u16* W1b  = (u16*)(ws + 82*MB);
  u16* W2b  = (u16*)(ws + 84*MB);

  const int M = 8192;

  cvt_all<<<1536, 256, 0, stream>>>(Wq, Wk, Wv, Wo, mW1, mW2, Wqkvb, Wob, W1b, W2b);

  ln512_kernel<<<2048, 256, 0, stream>>>(x, n1w, n1b, xn);

  gemm_bt<64,EPI_QSCALE,u16><<<dim3(12,128), 256, 0, stream>>>(xn, Wqkvb, nullptr, nullptr, qkv, M, 1536, 512);

  transpose_v<<<1024, 256, 0, stream>>>(qkv, vt);

  attn_mfma<<<1024, 256, 0, stream>>>(qkv, vt, lq1, lk1, lq2, lk2, subw, a);

  gemm_bt<64,EPI_NONE,u16><<<dim3(4,128), 256, 0, stream>>>(a, Wob, nullptr, nullptr, ao, M, 512, 512);

  lnres_kernel<<<2048, 256, 0, stream>>>(ao, x, n2w, n2b, m1w, m1b, h, z1);

  gemm_bt<64,EPI_BIAS_GELU,u16><<<dim3(16,128), 256, 0, stream>>>(z1, W1b, mb1, nullptr, t, M, 2048, 512);

  ln2048_kernel<<<2048, 256, 0, stream>>>(t, m2w, m2b, t);

  gemm_bt<64,EPI_BIAS_RES,float><<<dim3(4,128), 256, 0, stream>>>(t, W2b, mb2, h, out, M, 512, 2048);
}